// Round 12
// baseline (2767.619 us; speedup 1.0000x reference)
//
#include <hip/hip_runtime.h>
#include <hip/hip_bf16.h>
#include <math.h>

#define LSEQ 256
#define BB   64
#define EE   256

// ---------------- embedding gather: x0[r][e] = emb[tokens[r]][e] ----------------
__global__ __launch_bounds__(64)
void embed_kernel(const int* __restrict__ tokens, const float* __restrict__ emb,
                  float* __restrict__ x0) {
    int r = blockIdx.x;
    int tok = tokens[r];
    const float4* src = (const float4*)(emb + (size_t)tok * EE);
    float4* dst = (float4*)(x0 + (size_t)r * EE);
    dst[threadIdx.x] = src[threadIdx.x];
}

// ---- pack W_hh into W3[ld][ut(16)][k(256)][c(64)], c = g*16+ul, src w[(g*256+ut*16+ul)][k] ----
__global__ __launch_bounds__(256)
void pack_w3_kernel(const float* __restrict__ w0, const float* __restrict__ w1,
                    const float* __restrict__ w2, const float* __restrict__ w3,
                    float* __restrict__ W3) {
    __shared__ float t[16][65];
    const float* w = blockIdx.z == 0 ? w0 : blockIdx.z == 1 ? w1 : blockIdx.z == 2 ? w2 : w3;
    float* out = W3 + (size_t)blockIdx.z * 262144;
    int ut = blockIdx.y;
    int g = blockIdx.x >> 2, kt = blockIdx.x & 3;
    int k0 = kt * 64, tid = threadIdx.x;
    for (int e = tid; e < 1024; e += 256) {
        int ul = e >> 6, kl = e & 63;
        t[ul][kl] = w[(size_t)(g * 256 + ut * 16 + ul) * 256 + k0 + kl];
    }
    __syncthreads();
    for (int e = tid; e < 1024; e += 256) {
        int kl = e >> 4, ul = e & 15;
        out[(size_t)(ut * 256 + k0 + kl) * 64 + g * 16 + ul] = t[ul][kl];
    }
}

// ---------------- zero flag lines (dedicated region; runs every launch, graph-safe) ----------------
__global__ __launch_bounds__(256)
void init_flags_kernel(int* __restrict__ flags) {
    flags[blockIdx.x * 256 + threadIdx.x] = 0;
}

// ---------- merged dual GEMM: Cf/Cb[M,1024] = A[M,K] @ {Wf,Wb}[1024,K]^T + biases ----------
// grid (16 nb, 128 mb): nb<8 -> forward weights, else backward. x-fastest dispatch keeps the
// 16 n-tiles of one A m-tile temporally adjacent (A stays L2-hot). Double-buffered LDS:
// next tile's global loads issue BEFORE the compute phase -> ~500cyc HBM/L2 latency hides
// under the 1024 FMA/thread inner loop (the old kernel exposed it every BK=16 iteration).
__global__ __launch_bounds__(256)
void gemm_dual_kernel(const float* __restrict__ A,
                      const float* __restrict__ Wf, const float* __restrict__ Wb,
                      const float* __restrict__ b1f, const float* __restrict__ b2f,
                      const float* __restrict__ b1b, const float* __restrict__ b2b,
                      float* __restrict__ Cf, float* __restrict__ Cb, int K) {
    __shared__ float As[2][16][128];
    __shared__ float Bs[2][16][128];
    const int tid = threadIdx.x;
    const int nb = blockIdx.x;        // 0..15
    const int mb = blockIdx.y;        // 0..127
    const float* W; const float* bb1; const float* bb2; float* C; int bn;
    if (nb < 8) { W = Wf; bb1 = b1f; bb2 = b2f; C = Cf; bn = nb * 128; }
    else        { W = Wb; bb1 = b1b; bb2 = b2b; C = Cb; bn = (nb - 8) * 128; }
    const int bm = mb * 128;
    const int tm = (tid >> 4) << 3;
    const int tn = (tid & 15) << 3;
    const int lr = tid >> 1;
    const int lc = (tid & 1) << 3;
    const float* Ap = A + (size_t)(bm + lr) * K + lc;
    const float* Wp = W + (size_t)(bn + lr) * K + lc;

    float acc[8][8];
#pragma unroll
    for (int i = 0; i < 8; i++)
#pragma unroll
        for (int j = 0; j < 8; j++) acc[i][j] = 0.f;

    // preload iter 0 and stage into buffer 0
    float4 a0 = *(const float4*)(Ap);
    float4 a1 = *(const float4*)(Ap + 4);
    float4 w0 = *(const float4*)(Wp);
    float4 w1 = *(const float4*)(Wp + 4);
    As[0][lc+0][lr]=a0.x; As[0][lc+1][lr]=a0.y; As[0][lc+2][lr]=a0.z; As[0][lc+3][lr]=a0.w;
    As[0][lc+4][lr]=a1.x; As[0][lc+5][lr]=a1.y; As[0][lc+6][lr]=a1.z; As[0][lc+7][lr]=a1.w;
    Bs[0][lc+0][lr]=w0.x; Bs[0][lc+1][lr]=w0.y; Bs[0][lc+2][lr]=w0.z; Bs[0][lc+3][lr]=w0.w;
    Bs[0][lc+4][lr]=w1.x; Bs[0][lc+5][lr]=w1.y; Bs[0][lc+6][lr]=w1.z; Bs[0][lc+7][lr]=w1.w;
    __syncthreads();

    const int nIt = K >> 4;
    for (int it = 0; it < nIt; it++) {
        const int cur = it & 1;
        if (it + 1 < nIt) {                      // issue next tile's loads EARLY
            const int k0 = (it + 1) << 4;
            a0 = *(const float4*)(Ap + k0);
            a1 = *(const float4*)(Ap + k0 + 4);
            w0 = *(const float4*)(Wp + k0);
            w1 = *(const float4*)(Wp + k0 + 4);
        }
#pragma unroll
        for (int k = 0; k < 16; k++) {
            float av[8], bv[8];
            *(float4*)&av[0] = *(const float4*)&As[cur][k][tm];
            *(float4*)&av[4] = *(const float4*)&As[cur][k][tm+4];
            *(float4*)&bv[0] = *(const float4*)&Bs[cur][k][tn];
            *(float4*)&bv[4] = *(const float4*)&Bs[cur][k][tn+4];
#pragma unroll
            for (int i = 0; i < 8; i++)
#pragma unroll
                for (int j = 0; j < 8; j++) acc[i][j] = fmaf(av[i], bv[j], acc[i][j]);
        }
        if (it + 1 < nIt) {
            __syncthreads();                     // all threads done reading buf[cur^1]
            const int nxt = cur ^ 1;
            As[nxt][lc+0][lr]=a0.x; As[nxt][lc+1][lr]=a0.y; As[nxt][lc+2][lr]=a0.z; As[nxt][lc+3][lr]=a0.w;
            As[nxt][lc+4][lr]=a1.x; As[nxt][lc+5][lr]=a1.y; As[nxt][lc+6][lr]=a1.z; As[nxt][lc+7][lr]=a1.w;
            Bs[nxt][lc+0][lr]=w0.x; Bs[nxt][lc+1][lr]=w0.y; Bs[nxt][lc+2][lr]=w0.z; Bs[nxt][lc+3][lr]=w0.w;
            Bs[nxt][lc+4][lr]=w1.x; Bs[nxt][lc+5][lr]=w1.y; Bs[nxt][lc+6][lr]=w1.z; Bs[nxt][lc+7][lr]=w1.w;
            __syncthreads();
        }
    }
    float bj[8];
#pragma unroll
    for (int j = 0; j < 8; j++) bj[j] = bb1[bn+tn+j] + bb2[bn+tn+j];
#pragma unroll
    for (int i = 0; i < 8; i++) {
        float4 v0, v1;
        v0.x = acc[i][0]+bj[0]; v0.y = acc[i][1]+bj[1]; v0.z = acc[i][2]+bj[2]; v0.w = acc[i][3]+bj[3];
        v1.x = acc[i][4]+bj[4]; v1.y = acc[i][5]+bj[5]; v1.z = acc[i][6]+bj[6]; v1.w = acc[i][7]+bj[7];
        *(float4*)&C[(size_t)(bm+tm+i)*1024 + bn+tn]     = v0;
        *(float4*)&C[(size_t)(bm+tm+i)*1024 + bn+tn + 4] = v1;
    }
}

// ---------------- LSTM scan: r8-proven kernel, verbatim (845us/scan artifact) ----------------
__global__ __launch_bounds__(256, 1)
void lstm_scan_kernel(const float* __restrict__ Gf, const float* __restrict__ Gb,
                      const float* __restrict__ W3f, const float* __restrict__ W3b,
                      const int* __restrict__ lengths, float* __restrict__ xout,
                      float* __restrict__ hg, int* __restrict__ flags) {
    const int bid = blockIdx.x;
    const int dom = bid & 15;
    const int ut  = bid >> 4;
    const int dir = dom & 1;
    const int bt  = dom >> 1;
    const float* __restrict__ G = dir ? Gb : Gf;
    const float* __restrict__ W3 = (dir ? W3b : W3f) + (size_t)ut * 16384;
    float* hgD = hg + (size_t)dom * 4096;
    int* flgD  = flags + dom * 512;

    __shared__ float hs[2048];
    __shared__ float P[4096];

    const int tid = threadIdx.x;
    const int kg = tid >> 5, cw = tid & 31;
    const int w  = tid >> 6, lane = tid & 63;
    const int cb = (tid >> 4) & 7, cu = tid & 15;
    const int bg = bt * 8 + cb;
    const int ug = ut * 16 + cu;
    const int mylen = lengths[bg];

    float2 wreg[32];
#pragma unroll
    for (int kk = 0; kk < 32; kk++)
        wreg[kk] = *(const float2*)&W3[(size_t)(kg * 32 + kk) * 64 + cw * 2];

#pragma unroll
    for (int i = 0; i < 8; i++) hs[tid + 256 * i] = 0.f;

    float cstate = 0.f;
    int tcur = dir ? (mylen - 1) : 0;
    float gp0 = 0.f, gp1 = 0.f, gp2 = 0.f, gp3 = 0.f;
    if (tid < 128) {
        const float* gr = G + ((size_t)(tcur * BB + bg)) * 1024 + ug;
        gp0 = gr[0]; gp1 = gr[256]; gp2 = gr[512]; gp3 = gr[768];
    }
    __syncthreads();

    for (int s = 0; s < LSEQ; s++) {
        if (s > 0) {
            if (lane < 4) {
                const int* fp = &flgD[(4 * w + lane) * 32];
                while (__hip_atomic_load(fp, __ATOMIC_RELAXED, __HIP_MEMORY_SCOPE_AGENT) < s)
                    __builtin_amdgcn_s_sleep(1);
            }
            asm volatile("" ::: "memory");
            const unsigned long long* src =
                (const unsigned long long*)(hgD + ((s - 1) & 1) * 2048) + w * 256;
            unsigned long long v[4];
#pragma unroll
            for (int i = 0; i < 4; i++)
                v[i] = __hip_atomic_load(src + lane + 64 * i, __ATOMIC_RELAXED,
                                         __HIP_MEMORY_SCOPE_AGENT);
#pragma unroll
            for (int i = 0; i < 4; i++) {
                int fo = 512 * w + 2 * (lane + 64 * i);
                hs[fo]     = __uint_as_float((unsigned)v[i]);
                hs[fo + 1] = __uint_as_float((unsigned)(v[i] >> 32));
            }
            asm volatile("" ::: "memory");
        }

        float2 acc[8];
        const float4* h4 = (const float4*)hs;
#pragma unroll
        for (int b = 0; b < 8; b++) {
            float2 a = make_float2(0.f, 0.f);
            int hb0 = 64 * kg + 4 * b;
#pragma unroll
            for (int q = 0; q < 4; q++) {
                float4 hv = h4[hb0 + q];
                float2 w0 = wreg[q*4+0], w1 = wreg[q*4+1], w2 = wreg[q*4+2], w3v = wreg[q*4+3];
                a.x = fmaf(w0.x, hv.x, a.x); a.y = fmaf(w0.y, hv.x, a.y);
                a.x = fmaf(w1.x, hv.y, a.x); a.y = fmaf(w1.y, hv.y, a.y);
                a.x = fmaf(w2.x, hv.z, a.x); a.y = fmaf(w2.y, hv.z, a.y);
                a.x = fmaf(w3v.x, hv.w, a.x); a.y = fmaf(w3v.y, hv.w, a.y);
            }
#pragma unroll
            for (int q = 0; q < 4; q++) {
                float4 hv = h4[hb0 + 32 + q];
                float2 w0 = wreg[16+q*4+0], w1 = wreg[16+q*4+1], w2 = wreg[16+q*4+2], w3v = wreg[16+q*4+3];
                a.x = fmaf(w0.x, hv.x, a.x); a.y = fmaf(w0.y, hv.x, a.y);
                a.x = fmaf(w1.x, hv.y, a.x); a.y = fmaf(w1.y, hv.y, a.y);
                a.x = fmaf(w2.x, hv.z, a.x); a.y = fmaf(w2.y, hv.z, a.y);
                a.x = fmaf(w3v.x, hv.w, a.x); a.y = fmaf(w3v.y, hv.w, a.y);
            }
            acc[b] = a;
        }
        const int wofs = (cw * 2) ^ (kg * 2);
#pragma unroll
        for (int b = 0; b < 8; b++)
            *(float2*)&P[kg * 512 + b * 64 + wofs] = acc[b];
        __syncthreads();

        float h = 0.f;
        if (tid < 128) {
            float a0 = gp0, a1 = gp1, a2 = gp2, a3 = gp3;
#pragma unroll
            for (int k2 = 0; k2 < 8; k2++) {
                int base = k2 * 512 + cb * 64, x = k2 * 2;
                a0 += P[base + ((cu)      ^ x)];
                a1 += P[base + ((16 + cu) ^ x)];
                a2 += P[base + ((32 + cu) ^ x)];
                a3 += P[base + ((48 + cu) ^ x)];
            }
            float iv = 1.f / (1.f + expf(-a0));
            float fv = 1.f / (1.f + expf(-a1));
            float gv = tanhf(a2);
            float ov = 1.f / (1.f + expf(-a3));
            cstate = fv * cstate + iv * gv;
            h = ov * tanhf(cstate);
            float hp = __shfl_xor(h, 1);
            if (!(cu & 1)) {
                unsigned long long pv =
                    ((unsigned long long)__float_as_uint(hp) << 32) | __float_as_uint(h);
                atomicExch((unsigned long long*)&hgD[(s & 1) * 2048 + ut * 128 + cb * 16 + cu], pv);
            }
        }
        asm volatile("s_waitcnt vmcnt(0)" ::: "memory");
        __syncthreads();
        if (tid == 0) atomicExch(&flgD[ut * 32], s + 1);
        if (tid < 128) {
            xout[(size_t)(tcur * BB + bg) * 512 + dir * 256 + ug] = (s < mylen) ? h : 0.f;
            if (s < LSEQ - 1) {
                int s2 = s + 1;
                tcur = dir ? (s2 < mylen ? mylen - 1 - s2 : s2) : s2;
                const float* gr = G + ((size_t)(tcur * BB + bg)) * 1024 + ug;
                gp0 = gr[0]; gp1 = gr[256]; gp2 = gr[512]; gp3 = gr[768];
            }
        }
    }
}

// ---------------- emissions: em[r][n] = x[r]·w_out[n] + b_out[n] ----------------
__global__ __launch_bounds__(256)
void emis_kernel(const float* __restrict__ x, const float* __restrict__ w_out,
                 const float* __restrict__ b_out, float* __restrict__ em) {
    __shared__ float ws_[16][516];
    __shared__ float xs[16][516];
    int tid = threadIdx.x;
    size_t r0 = (size_t)blockIdx.x * 16;
    for (int i4 = tid; i4 < 2048; i4 += 256) {
        int r = i4 >> 7, k4 = (i4 & 127) << 2;
        *(float4*)&ws_[r][k4] = *(const float4*)&w_out[r*512 + k4];
        *(float4*)&xs[r][k4]  = *(const float4*)&x[(r0 + r)*512 + k4];
    }
    __syncthreads();
    int rr = tid >> 4, n = tid & 15;
    const float4* xr = (const float4*)&xs[rr][0];
    const float4* wr = (const float4*)&ws_[n][0];
    float4 s; s.x = s.y = s.z = s.w = 0.f;
#pragma unroll 8
    for (int k = 0; k < 128; k++) {
        float4 a = xr[k], b = wr[k];
        s.x = fmaf(a.x,b.x,s.x); s.y = fmaf(a.y,b.y,s.y);
        s.z = fmaf(a.z,b.z,s.z); s.w = fmaf(a.w,b.w,s.w);
    }
    em[(r0+rr)*16 + n] = s.x+s.y+s.z+s.w + b_out[n];
}

// ---------------- CRF Viterbi decode, one block per batch element ----------------
__global__ __launch_bounds__(64)
void viterbi_kernel(const float* __restrict__ em, const int* __restrict__ tokens,
                    const float* __restrict__ start_trans, const float* __restrict__ end_trans,
                    const float* __restrict__ trans, float* __restrict__ out) {
    __shared__ float em_s[256][16];
    __shared__ float tr_s[16][16];
    __shared__ float sc[16];
    __shared__ unsigned char hist[255][16];
    int b = blockIdx.x, tid = threadIdx.x;
    for (int i = tid; i < 4096; i += 64) {
        int t = i >> 4, n = i & 15;
        em_s[t][n] = em[(size_t)t*1024 + b*16 + n];
    }
    for (int i = tid; i < 256; i += 64) ((float*)tr_s)[i] = trans[i];
    __syncthreads();
    if (tid < 16) sc[tid] = start_trans[tid] + em_s[0][tid];
    __syncthreads();
    for (int t = 1; t < 256; t++) {
        float best = 0.f; int arg = 0;
        if (tid < 16) {
            best = sc[0] + tr_s[0][tid];
#pragma unroll
            for (int i = 1; i < 16; i++) {
                float v = sc[i] + tr_s[i][tid];
                if (v > best) { best = v; arg = i; }
            }
            best += em_s[t][tid];
            hist[t-1][tid] = (unsigned char)arg;
        }
        bool m = tokens[t*64 + b] != 0;
        __syncthreads();
        if (tid < 16 && m) sc[tid] = best;
        __syncthreads();
    }
    if (tid == 0) {
        float best = sc[0] + end_trans[0]; int cur = 0;
        for (int jj = 1; jj < 16; jj++) {
            float v = sc[jj] + end_trans[jj];
            if (v > best) { best = v; cur = jj; }
        }
        out[b] = best;
        float* tags = out + 64;
        tags[255*64 + b] = (tokens[255*64+b] != 0) ? (float)cur : 0.f;
        for (int t = 254; t >= 0; t--) {
            if (tokens[(t+1)*64 + b] != 0) cur = hist[t][cur];
            tags[t*64 + b] = (tokens[t*64+b] != 0) ? (float)cur : 0.f;
        }
    }
}

extern "C" void kernel_launch(void* const* d_in, const int* in_sizes, int n_in,
                              void* d_out, int out_size, void* d_ws, size_t ws_size,
                              hipStream_t stream) {
    const int*   tokens   = (const int*)d_in[0];
    const int*   lengths  = (const int*)d_in[1];
    const float* emb      = (const float*)d_in[2];
    const float* w_ih_l0f = (const float*)d_in[3];
    const float* w_hh_l0f = (const float*)d_in[4];
    const float* b_ih_l0f = (const float*)d_in[5];
    const float* b_hh_l0f = (const float*)d_in[6];
    const float* w_ih_l0b = (const float*)d_in[7];
    const float* w_hh_l0b = (const float*)d_in[8];
    const float* b_ih_l0b = (const float*)d_in[9];
    const float* b_hh_l0b = (const float*)d_in[10];
    const float* w_ih_l1f = (const float*)d_in[11];
    const float* w_hh_l1f = (const float*)d_in[12];
    const float* b_ih_l1f = (const float*)d_in[13];
    const float* b_hh_l1f = (const float*)d_in[14];
    const float* w_ih_l1b = (const float*)d_in[15];
    const float* w_hh_l1b = (const float*)d_in[16];
    const float* b_ih_l1b = (const float*)d_in[17];
    const float* b_hh_l1b = (const float*)d_in[18];
    const float* w_out    = (const float*)d_in[19];
    const float* b_out    = (const float*)d_in[20];
    const float* start_tr = (const float*)d_in[21];
    const float* end_tr   = (const float*)d_in[22];
    const float* trans    = (const float*)d_in[23];

    // workspace layout (floats) — dedicated regions for hg/flags (r10 overlay bug avoided)
    float* ws   = (float*)d_ws;
    float* x0   = ws;                        // [16384][256]; em overlays after GEMM0
    float* x12  = x0 + 4194304;              // [16384][512]: x1, then x2 (in-place swap at scan1)
    float* Gf   = x12 + 8388608;             // [16384][1024]: G0f, then G1f (kernel-boundary reuse)
    float* Gb   = Gf + 16777216;             // [16384][1024]: G0b -> G1b
    float* W3   = Gb + 16777216;             // 4 x [16][256][64] packed W_hh
    float* W30f = W3, *W30b = W3 + 262144, *W31f = W3 + 524288, *W31b = W3 + 786432;
    float* hg   = W3 + 1048576;              // [16 dom][2 par][2048] = 65536 floats
    int*   flags = (int*)(hg + 65536);       // 2 scans x 8192 ints
    float* em   = x0;                        // [16384][16] overlay (x0 dead after GEMM0)

    embed_kernel<<<16384, 64, 0, stream>>>(tokens, emb, x0);
    pack_w3_kernel<<<dim3(16, 16, 4), 256, 0, stream>>>(w_hh_l0f, w_hh_l0b, w_hh_l1f, w_hh_l1b, W3);
    init_flags_kernel<<<64, 256, 0, stream>>>(flags);

    // layer-0 G: merged f+b dual GEMM (K=256)
    gemm_dual_kernel<<<dim3(16, 128), 256, 0, stream>>>(
        x0, w_ih_l0f, w_ih_l0b, b_ih_l0f, b_hh_l0f, b_ih_l0b, b_hh_l0b, Gf, Gb, 256);
    lstm_scan_kernel<<<256, 256, 0, stream>>>(Gf, Gb, W30f, W30b, lengths, x12, hg, flags);

    // layer-1 G: merged dual GEMM (K=512), overwrites G0 storage (scan0 complete)
    gemm_dual_kernel<<<dim3(16, 128), 256, 0, stream>>>(
        x12, w_ih_l1f, w_ih_l1b, b_ih_l1f, b_hh_l1f, b_ih_l1b, b_hh_l1b, Gf, Gb, 512);
    lstm_scan_kernel<<<256, 256, 0, stream>>>(Gf, Gb, W31f, W31b, lengths, x12, hg, flags + 8192);

    emis_kernel<<<1024, 256, 0, stream>>>(x12, w_out, b_out, em);
    viterbi_kernel<<<64, 64, 0, stream>>>(em, tokens, start_tr, end_tr, trans, (float*)d_out);
}

// Round 13
// 2361.302 us; speedup vs baseline: 1.1721x; 1.1721x over previous
//
#include <hip/hip_runtime.h>
#include <hip/hip_bf16.h>
#include <math.h>

#define LSEQ 256
#define BB   64
#define EE   256

// ---------------- embedding gather: x0[r][e] = emb[tokens[r]][e]  (4 rows/block) ----------------
__global__ __launch_bounds__(256)
void embed_kernel(const int* __restrict__ tokens, const float* __restrict__ emb,
                  float* __restrict__ x0) {
    int r = blockIdx.x * 4 + (threadIdx.x >> 6);   // 4096 blocks x 4 rows
    int lane4 = threadIdx.x & 63;
    int tok = tokens[r];
    ((float4*)(x0 + (size_t)r * EE))[lane4] =
        ((const float4*)(emb + (size_t)tok * EE))[lane4];
}

// ---- pack W_hh into W3[ld][ut(16)][k(256)][c(64)], c = g*16+ul, src w[(g*256+ut*16+ul)][k] ----
__global__ __launch_bounds__(256)
void pack_w3_kernel(const float* __restrict__ w0, const float* __restrict__ w1,
                    const float* __restrict__ w2, const float* __restrict__ w3,
                    float* __restrict__ W3) {
    __shared__ float t[16][65];
    const float* w = blockIdx.z == 0 ? w0 : blockIdx.z == 1 ? w1 : blockIdx.z == 2 ? w2 : w3;
    float* out = W3 + (size_t)blockIdx.z * 262144;
    int ut = blockIdx.y;
    int g = blockIdx.x >> 2, kt = blockIdx.x & 3;
    int k0 = kt * 64, tid = threadIdx.x;
    for (int e = tid; e < 1024; e += 256) {
        int ul = e >> 6, kl = e & 63;
        t[ul][kl] = w[(size_t)(g * 256 + ut * 16 + ul) * 256 + k0 + kl];
    }
    __syncthreads();
    for (int e = tid; e < 1024; e += 256) {
        int kl = e >> 4, ul = e & 15;
        out[(size_t)(ut * 256 + k0 + kl) * 64 + g * 16 + ul] = t[ul][kl];
    }
}

// ---------------- zero flag lines (dedicated region; runs every launch, graph-safe) ----------------
__global__ __launch_bounds__(256)
void init_flags_kernel(int* __restrict__ flags) {
    flags[blockIdx.x * 256 + threadIdx.x] = 0;
}

// ---------------- C[M,N] = A[M,K] @ W[N,K]^T + b1[N] + b2[N] ----------------
// r8 structure exactly (single 8KB buffer, same barriers, mb-fastest grid), ONE change:
// next tile's global loads issue right AFTER staging (hidden under the 2048-cyc FMA
// phase) instead of right before it (where r8 exposed the full load latency at the
// staging s_waitcnt every BK=16 iteration).
__global__ __launch_bounds__(256)
void gemm_bias_kernel(const float* __restrict__ A, const float* __restrict__ W,
                      const float* __restrict__ b1, const float* __restrict__ b2,
                      float* __restrict__ C, int M, int N, int K) {
    const int BK = 16;
    __shared__ float As[BK][128];
    __shared__ float Bs[BK][128];
    int tid = threadIdx.x;
    int bm = blockIdx.x * 128;
    int bn = blockIdx.y * 128;
    int tm = (tid >> 4) << 3;
    int tn = (tid & 15) << 3;
    int lr = tid >> 1;
    int lc = (tid & 1) << 3;
    const float* Ap = A + (size_t)(bm + lr) * K + lc;
    const float* Wpt = W + (size_t)(bn + lr) * K + lc;
    float acc[8][8];
#pragma unroll
    for (int i = 0; i < 8; i++)
#pragma unroll
        for (int j = 0; j < 8; j++) acc[i][j] = 0.f;

    // preload tile 0
    float4 a0 = *(const float4*)(Ap);
    float4 a1 = *(const float4*)(Ap + 4);
    float4 w0 = *(const float4*)(Wpt);
    float4 w1 = *(const float4*)(Wpt + 4);

    const int nIt = K >> 4;
    for (int it = 0; it < nIt; it++) {
        __syncthreads();                         // prev compute done reading LDS
        As[lc+0][lr]=a0.x; As[lc+1][lr]=a0.y; As[lc+2][lr]=a0.z; As[lc+3][lr]=a0.w;
        As[lc+4][lr]=a1.x; As[lc+5][lr]=a1.y; As[lc+6][lr]=a1.z; As[lc+7][lr]=a1.w;
        Bs[lc+0][lr]=w0.x; Bs[lc+1][lr]=w0.y; Bs[lc+2][lr]=w0.z; Bs[lc+3][lr]=w0.w;
        Bs[lc+4][lr]=w1.x; Bs[lc+5][lr]=w1.y; Bs[lc+6][lr]=w1.z; Bs[lc+7][lr]=w1.w;
        __syncthreads();
        if (it + 1 < nIt) {                      // issue next tile EARLY (hidden by FMAs)
            const int k0 = (it + 1) << 4;
            a0 = *(const float4*)(Ap + k0);
            a1 = *(const float4*)(Ap + k0 + 4);
            w0 = *(const float4*)(Wpt + k0);
            w1 = *(const float4*)(Wpt + k0 + 4);
        }
#pragma unroll
        for (int k = 0; k < BK; k++) {
            float av[8], bv[8];
            *(float4*)&av[0] = *(const float4*)&As[k][tm];
            *(float4*)&av[4] = *(const float4*)&As[k][tm+4];
            *(float4*)&bv[0] = *(const float4*)&Bs[k][tn];
            *(float4*)&bv[4] = *(const float4*)&Bs[k][tn+4];
#pragma unroll
            for (int i = 0; i < 8; i++)
#pragma unroll
                for (int j = 0; j < 8; j++) acc[i][j] = fmaf(av[i], bv[j], acc[i][j]);
        }
    }
    float bj[8];
#pragma unroll
    for (int j = 0; j < 8; j++) bj[j] = b1[bn+tn+j] + b2[bn+tn+j];
#pragma unroll
    for (int i = 0; i < 8; i++) {
        float4 v0, v1;
        v0.x = acc[i][0]+bj[0]; v0.y = acc[i][1]+bj[1]; v0.z = acc[i][2]+bj[2]; v0.w = acc[i][3]+bj[3];
        v1.x = acc[i][4]+bj[4]; v1.y = acc[i][5]+bj[5]; v1.z = acc[i][6]+bj[6]; v1.w = acc[i][7]+bj[7];
        *(float4*)&C[(size_t)(bm+tm+i)*N + bn+tn]     = v0;
        *(float4*)&C[(size_t)(bm+tm+i)*N + bn+tn + 4] = v1;
    }
}

// ---------------- LSTM scan: r8-proven kernel, verbatim (845us/scan artifact) ----------------
__global__ __launch_bounds__(256, 1)
void lstm_scan_kernel(const float* __restrict__ Gf, const float* __restrict__ Gb,
                      const float* __restrict__ W3f, const float* __restrict__ W3b,
                      const int* __restrict__ lengths, float* __restrict__ xout,
                      float* __restrict__ hg, int* __restrict__ flags) {
    const int bid = blockIdx.x;
    const int dom = bid & 15;
    const int ut  = bid >> 4;
    const int dir = dom & 1;
    const int bt  = dom >> 1;
    const float* __restrict__ G = dir ? Gb : Gf;
    const float* __restrict__ W3 = (dir ? W3b : W3f) + (size_t)ut * 16384;
    float* hgD = hg + (size_t)dom * 4096;
    int* flgD  = flags + dom * 512;

    __shared__ float hs[2048];
    __shared__ float P[4096];

    const int tid = threadIdx.x;
    const int kg = tid >> 5, cw = tid & 31;
    const int w  = tid >> 6, lane = tid & 63;
    const int cb = (tid >> 4) & 7, cu = tid & 15;
    const int bg = bt * 8 + cb;
    const int ug = ut * 16 + cu;
    const int mylen = lengths[bg];

    float2 wreg[32];
#pragma unroll
    for (int kk = 0; kk < 32; kk++)
        wreg[kk] = *(const float2*)&W3[(size_t)(kg * 32 + kk) * 64 + cw * 2];

#pragma unroll
    for (int i = 0; i < 8; i++) hs[tid + 256 * i] = 0.f;

    float cstate = 0.f;
    int tcur = dir ? (mylen - 1) : 0;
    float gp0 = 0.f, gp1 = 0.f, gp2 = 0.f, gp3 = 0.f;
    if (tid < 128) {
        const float* gr = G + ((size_t)(tcur * BB + bg)) * 1024 + ug;
        gp0 = gr[0]; gp1 = gr[256]; gp2 = gr[512]; gp3 = gr[768];
    }
    __syncthreads();

    for (int s = 0; s < LSEQ; s++) {
        if (s > 0) {
            if (lane < 4) {
                const int* fp = &flgD[(4 * w + lane) * 32];
                while (__hip_atomic_load(fp, __ATOMIC_RELAXED, __HIP_MEMORY_SCOPE_AGENT) < s)
                    __builtin_amdgcn_s_sleep(1);
            }
            asm volatile("" ::: "memory");
            const unsigned long long* src =
                (const unsigned long long*)(hgD + ((s - 1) & 1) * 2048) + w * 256;
            unsigned long long v[4];
#pragma unroll
            for (int i = 0; i < 4; i++)
                v[i] = __hip_atomic_load(src + lane + 64 * i, __ATOMIC_RELAXED,
                                         __HIP_MEMORY_SCOPE_AGENT);
#pragma unroll
            for (int i = 0; i < 4; i++) {
                int fo = 512 * w + 2 * (lane + 64 * i);
                hs[fo]     = __uint_as_float((unsigned)v[i]);
                hs[fo + 1] = __uint_as_float((unsigned)(v[i] >> 32));
            }
            asm volatile("" ::: "memory");
        }

        float2 acc[8];
        const float4* h4 = (const float4*)hs;
#pragma unroll
        for (int b = 0; b < 8; b++) {
            float2 a = make_float2(0.f, 0.f);
            int hb0 = 64 * kg + 4 * b;
#pragma unroll
            for (int q = 0; q < 4; q++) {
                float4 hv = h4[hb0 + q];
                float2 w0 = wreg[q*4+0], w1 = wreg[q*4+1], w2 = wreg[q*4+2], w3v = wreg[q*4+3];
                a.x = fmaf(w0.x, hv.x, a.x); a.y = fmaf(w0.y, hv.x, a.y);
                a.x = fmaf(w1.x, hv.y, a.x); a.y = fmaf(w1.y, hv.y, a.y);
                a.x = fmaf(w2.x, hv.z, a.x); a.y = fmaf(w2.y, hv.z, a.y);
                a.x = fmaf(w3v.x, hv.w, a.x); a.y = fmaf(w3v.y, hv.w, a.y);
            }
#pragma unroll
            for (int q = 0; q < 4; q++) {
                float4 hv = h4[hb0 + 32 + q];
                float2 w0 = wreg[16+q*4+0], w1 = wreg[16+q*4+1], w2 = wreg[16+q*4+2], w3v = wreg[16+q*4+3];
                a.x = fmaf(w0.x, hv.x, a.x); a.y = fmaf(w0.y, hv.x, a.y);
                a.x = fmaf(w1.x, hv.y, a.x); a.y = fmaf(w1.y, hv.y, a.y);
                a.x = fmaf(w2.x, hv.z, a.x); a.y = fmaf(w2.y, hv.z, a.y);
                a.x = fmaf(w3v.x, hv.w, a.x); a.y = fmaf(w3v.y, hv.w, a.y);
            }
            acc[b] = a;
        }
        const int wofs = (cw * 2) ^ (kg * 2);
#pragma unroll
        for (int b = 0; b < 8; b++)
            *(float2*)&P[kg * 512 + b * 64 + wofs] = acc[b];
        __syncthreads();

        float h = 0.f;
        if (tid < 128) {
            float a0 = gp0, a1 = gp1, a2 = gp2, a3 = gp3;
#pragma unroll
            for (int k2 = 0; k2 < 8; k2++) {
                int base = k2 * 512 + cb * 64, x = k2 * 2;
                a0 += P[base + ((cu)      ^ x)];
                a1 += P[base + ((16 + cu) ^ x)];
                a2 += P[base + ((32 + cu) ^ x)];
                a3 += P[base + ((48 + cu) ^ x)];
            }
            float iv = 1.f / (1.f + expf(-a0));
            float fv = 1.f / (1.f + expf(-a1));
            float gv = tanhf(a2);
            float ov = 1.f / (1.f + expf(-a3));
            cstate = fv * cstate + iv * gv;
            h = ov * tanhf(cstate);
            float hp = __shfl_xor(h, 1);
            if (!(cu & 1)) {
                unsigned long long pv =
                    ((unsigned long long)__float_as_uint(hp) << 32) | __float_as_uint(h);
                atomicExch((unsigned long long*)&hgD[(s & 1) * 2048 + ut * 128 + cb * 16 + cu], pv);
            }
        }
        asm volatile("s_waitcnt vmcnt(0)" ::: "memory");
        __syncthreads();
        if (tid == 0) atomicExch(&flgD[ut * 32], s + 1);
        if (tid < 128) {
            xout[(size_t)(tcur * BB + bg) * 512 + dir * 256 + ug] = (s < mylen) ? h : 0.f;
            if (s < LSEQ - 1) {
                int s2 = s + 1;
                tcur = dir ? (s2 < mylen ? mylen - 1 - s2 : s2) : s2;
                const float* gr = G + ((size_t)(tcur * BB + bg)) * 1024 + ug;
                gp0 = gr[0]; gp1 = gr[256]; gp2 = gr[512]; gp3 = gr[768];
            }
        }
    }
}

// ---------------- emissions: em[r][n] = x[r]·w_out[n] + b_out[n] ----------------
__global__ __launch_bounds__(256)
void emis_kernel(const float* __restrict__ x, const float* __restrict__ w_out,
                 const float* __restrict__ b_out, float* __restrict__ em) {
    __shared__ float ws_[16][516];
    __shared__ float xs[16][516];
    int tid = threadIdx.x;
    size_t r0 = (size_t)blockIdx.x * 16;
    for (int i4 = tid; i4 < 2048; i4 += 256) {
        int r = i4 >> 7, k4 = (i4 & 127) << 2;
        *(float4*)&ws_[r][k4] = *(const float4*)&w_out[r*512 + k4];
        *(float4*)&xs[r][k4]  = *(const float4*)&x[(r0 + r)*512 + k4];
    }
    __syncthreads();
    int rr = tid >> 4, n = tid & 15;
    const float4* xr = (const float4*)&xs[rr][0];
    const float4* wr = (const float4*)&ws_[n][0];
    float4 s; s.x = s.y = s.z = s.w = 0.f;
#pragma unroll 8
    for (int k = 0; k < 128; k++) {
        float4 a = xr[k], b = wr[k];
        s.x = fmaf(a.x,b.x,s.x); s.y = fmaf(a.y,b.y,s.y);
        s.z = fmaf(a.z,b.z,s.z); s.w = fmaf(a.w,b.w,s.w);
    }
    em[(r0+rr)*16 + n] = s.x+s.y+s.z+s.w + b_out[n];
}

// ---------------- CRF Viterbi decode, one block per batch element ----------------
__global__ __launch_bounds__(64)
void viterbi_kernel(const float* __restrict__ em, const int* __restrict__ tokens,
                    const float* __restrict__ start_trans, const float* __restrict__ end_trans,
                    const float* __restrict__ trans, float* __restrict__ out) {
    __shared__ float em_s[256][16];
    __shared__ float tr_s[16][16];
    __shared__ float sc[16];
    __shared__ unsigned char hist[255][16];
    int b = blockIdx.x, tid = threadIdx.x;
    for (int i = tid; i < 4096; i += 64) {
        int t = i >> 4, n = i & 15;
        em_s[t][n] = em[(size_t)t*1024 + b*16 + n];
    }
    for (int i = tid; i < 256; i += 64) ((float*)tr_s)[i] = trans[i];
    __syncthreads();
    if (tid < 16) sc[tid] = start_trans[tid] + em_s[0][tid];
    __syncthreads();
    for (int t = 1; t < 256; t++) {
        float best = 0.f; int arg = 0;
        if (tid < 16) {
            best = sc[0] + tr_s[0][tid];
#pragma unroll
            for (int i = 1; i < 16; i++) {
                float v = sc[i] + tr_s[i][tid];
                if (v > best) { best = v; arg = i; }
            }
            best += em_s[t][tid];
            hist[t-1][tid] = (unsigned char)arg;
        }
        bool m = tokens[t*64 + b] != 0;
        __syncthreads();
        if (tid < 16 && m) sc[tid] = best;
        __syncthreads();
    }
    if (tid == 0) {
        float best = sc[0] + end_trans[0]; int cur = 0;
        for (int jj = 1; jj < 16; jj++) {
            float v = sc[jj] + end_trans[jj];
            if (v > best) { best = v; cur = jj; }
        }
        out[b] = best;
        float* tags = out + 64;
        tags[255*64 + b] = (tokens[255*64+b] != 0) ? (float)cur : 0.f;
        for (int t = 254; t >= 0; t--) {
            if (tokens[(t+1)*64 + b] != 0) cur = hist[t][cur];
            tags[t*64 + b] = (tokens[t*64+b] != 0) ? (float)cur : 0.f;
        }
    }
}

extern "C" void kernel_launch(void* const* d_in, const int* in_sizes, int n_in,
                              void* d_out, int out_size, void* d_ws, size_t ws_size,
                              hipStream_t stream) {
    const int*   tokens   = (const int*)d_in[0];
    const int*   lengths  = (const int*)d_in[1];
    const float* emb      = (const float*)d_in[2];
    const float* w_ih_l0f = (const float*)d_in[3];
    const float* w_hh_l0f = (const float*)d_in[4];
    const float* b_ih_l0f = (const float*)d_in[5];
    const float* b_hh_l0f = (const float*)d_in[6];
    const float* w_ih_l0b = (const float*)d_in[7];
    const float* w_hh_l0b = (const float*)d_in[8];
    const float* b_ih_l0b = (const float*)d_in[9];
    const float* b_hh_l0b = (const float*)d_in[10];
    const float* w_ih_l1f = (const float*)d_in[11];
    const float* w_hh_l1f = (const float*)d_in[12];
    const float* b_ih_l1f = (const float*)d_in[13];
    const float* b_hh_l1f = (const float*)d_in[14];
    const float* w_ih_l1b = (const float*)d_in[15];
    const float* w_hh_l1b = (const float*)d_in[16];
    const float* b_ih_l1b = (const float*)d_in[17];
    const float* b_hh_l1b = (const float*)d_in[18];
    const float* w_out    = (const float*)d_in[19];
    const float* b_out    = (const float*)d_in[20];
    const float* start_tr = (const float*)d_in[21];
    const float* end_tr   = (const float*)d_in[22];
    const float* trans    = (const float*)d_in[23];

    // workspace layout (floats) — dedicated hg/flags regions (r10 overlay bug avoided)
    float* ws   = (float*)d_ws;
    float* x0   = ws;                        // [16384][256]; em overlays after GEMM0
    float* x12  = x0 + 4194304;              // [16384][512]: x1, then x2
    float* Gf   = x12 + 8388608;             // [16384][1024]: G0f -> G1f
    float* Gb   = Gf + 16777216;             // [16384][1024]: G0b -> G1b
    float* W3   = Gb + 16777216;             // 4 x [16][256][64] packed W_hh
    float* W30f = W3, *W30b = W3 + 262144, *W31f = W3 + 524288, *W31b = W3 + 786432;
    float* hg   = W3 + 1048576;              // [16 dom][2 par][2048] = 65536 floats
    int*   flags = (int*)(hg + 65536);       // 2 scans x 8192 ints
    float* em   = x0;                        // [16384][16] overlay (x0 dead after GEMM0)

    embed_kernel<<<4096, 256, 0, stream>>>(tokens, emb, x0);
    pack_w3_kernel<<<dim3(16, 16, 4), 256, 0, stream>>>(w_hh_l0f, w_hh_l0b, w_hh_l1f, w_hh_l1b, W3);
    init_flags_kernel<<<64, 256, 0, stream>>>(flags);

    dim3 gg(128, 8);
    gemm_bias_kernel<<<gg, 256, 0, stream>>>(x0, w_ih_l0f, b_ih_l0f, b_hh_l0f, Gf, 16384, 1024, 256);
    gemm_bias_kernel<<<gg, 256, 0, stream>>>(x0, w_ih_l0b, b_ih_l0b, b_hh_l0b, Gb, 16384, 1024, 256);
    lstm_scan_kernel<<<256, 256, 0, stream>>>(Gf, Gb, W30f, W30b, lengths, x12, hg, flags);

    gemm_bias_kernel<<<gg, 256, 0, stream>>>(x12, w_ih_l1f, b_ih_l1f, b_hh_l1f, Gf, 16384, 1024, 512);
    gemm_bias_kernel<<<gg, 256, 0, stream>>>(x12, w_ih_l1b, b_ih_l1b, b_hh_l1b, Gb, 16384, 1024, 512);
    lstm_scan_kernel<<<256, 256, 0, stream>>>(Gf, Gb, W31f, W31b, lengths, x12, hg, flags + 8192);

    emis_kernel<<<1024, 256, 0, stream>>>(x12, w_out, b_out, em);
    viterbi_kernel<<<64, 64, 0, stream>>>(em, tokens, start_tr, end_tr, trans, (float*)d_out);
}